// Round 9
// baseline (7661.378 us; speedup 1.0000x reference)
//
#include <hip/hip_runtime.h>
#include <stdint.h>
#include <stddef.h>

// Persistent 2-layer LSTM decoder, B=1024, H=256, T=512.
//
// R13: 4 waves/SIMD via 2 DECORRELATED blocks/CU. R12 (512-thr block, 2
// waves/SIMD same block) proved the stall is per-wave exposed latency:
// 4879 -> 3340us, but its 2 waves stall TOGETHER at every __syncthreads /
// group barrier (6+2 per step) — ~9k of 15.7k cyc/step still idle. Fix:
// halve the group (32 groups x 32 chains), 512 blocks x 512 threads,
// 2 blocks/CU from DIFFERENT groups (slot-claim: slots i, i+32 differ in
// group) — each block's sync/barrier stalls are covered by the other
// group's block. Per-CU work unchanged.
// Feasibility (the R6/R9 blocker, solved by R12's layout): one gate tile
// per wave = 104 weight VGPRs, R12 measured 124 total <= 128 = the 4-wave
// budget. LDS diet to 77.5K <= 80K: sb0/sb1 16K each (half group), Wfc
// 33.3K padded, exch/predbuf UNIONED (time-disjoint, barrier-separated),
// predbuf stride 65 (reads 2-way free, was 8-way at stride 68).
//  - barrier: R4-R12-proven RMW arrive/poll + buffer_inv sc0 acquire.
//  - staging: sb0 <- h0(t) after b1 (serves L1(t) + L0(t+1)); sb1 <- h1(t)
//    after b2 (serves L1(t+1)); FC reads h1 from L2 directly.
//  - elementwise: 512 threads x 1 (chain, unit) entry; c-state in regs.
//
// h-buffer layout (per group, per layer): chunked f16
//   f16_index = (c*32 + m)*8 + e, c = unit/8 (0..31), m = chain (0..31),
//   e = unit%8. A-fragment = one 16B chunk; chunk c = contiguous 512B
//   (=> linear global_load_lds).

#define NGROUP 32
#define GWG    16
#define NTHR   512
#define TSTEPS 512

typedef _Float16 half8 __attribute__((ext_vector_type(8)));
typedef float    f32x4 __attribute__((ext_vector_type(4)));

#define OUT_ELEMS   33554432   // 1024*512*64
#define HF_ELEMS    524288     // 2*1024*256
#define HBUF_ELEMS  8192       // 32*256 (f16) per layer (16KB)
#define GROUP_WS_BYTES 32768   // 2 layers * 16KB
#define WS_SLOT_OFF 4096       // per-XCD slot counters (ctrs use 0..4095)
#define WS_HBUF_OFF 8192
#define WS_NEEDED   (WS_HBUF_OFF + NGROUP * GROUP_WS_BYTES)

__device__ __forceinline__ float sigm(float x)   { return 1.0f / (1.0f + __expf(-x)); }
__device__ __forceinline__ float tanh_f(float x) { return 1.0f - 2.0f / (__expf(2.0f * x) + 1.0f); }

// XCD-local group barrier (R4-R12 proven RMW mechanism). Entry __syncthreads
// drains vmcnt (write-through L1 => prior h stores in XCD L2). Arrive/poll
// are real RMWs at the L2 (zz = opaque zero defeats the atomicrmw-add-0 ->
// load fold). Acquire = L1-only invalidate, then block rendezvous.
__device__ __forceinline__ void group_barrier(int* ctr, int* phase, int zz) {
  __syncthreads();
  if (threadIdx.x == 0) {
    __hip_atomic_fetch_add(ctr, 1, __ATOMIC_RELEASE, __HIP_MEMORY_SCOPE_WORKGROUP);
    const int target = GWG * (++(*phase));
    while (__hip_atomic_fetch_add(ctr, zz, __ATOMIC_RELAXED, __HIP_MEMORY_SCOPE_WORKGROUP) < target)
      __builtin_amdgcn_s_sleep(1);
    asm volatile("buffer_inv sc0" ::: "memory");   // L1-only invalidate (gfx940+)
  }
  __syncthreads();
}

// 16B A-fragment plain load from a chunked h-buffer in L2.
__device__ __forceinline__ half8 ld_frag(const _Float16* buf, int idx16) {
  return *(const half8*)(buf + (size_t)idx16 * 8);
}

// 16KB linear global->LDS copy, zero VGPR destination, 8 waves x 2 insts.
// LDS dest = wave-uniform base + lane*16 (m97/m104 semantics).
__device__ __forceinline__ void stage16k8(const void* src, void* lds_dst, int tid) {
  const int wv = tid >> 6;
  const int ln = tid & 63;
  const char* s = (const char*)src + ln * 16;
  char* d = (char*)lds_dst;
  #pragma unroll
  for (int i = 0; i < 2; ++i) {
    const int off = (i * 8 + wv) * 1024;
    __builtin_amdgcn_global_load_lds(
        (const __attribute__((address_space(1))) void*)(s + off),
        (__attribute__((address_space(3))) void*)(d + off),
        16, 0, 0);
  }
}

__global__ __launch_bounds__(NTHR, 4)   // 4 waves/EU => 2 blocks/CU, VGPR<=128
void decoder_kernel(const float* __restrict__ h0in, const float* __restrict__ c0in,
                    const float* __restrict__ Wih0, const float* __restrict__ Whh0,
                    const float* __restrict__ bih0, const float* __restrict__ bhh0,
                    const float* __restrict__ Wih1, const float* __restrict__ Whh1,
                    const float* __restrict__ bih1, const float* __restrict__ bhh1,
                    const float* __restrict__ Wfc,  const float* __restrict__ bfc,
                    float* __restrict__ out, char* __restrict__ ws)
{
  const int tid  = threadIdx.x;
  const int lane = tid & 63;
  const int wave = tid >> 6;    // 0..7
  const int mi   = wave >> 2;   // chain half (16 chains each)
  const int nj   = wave & 3;    // gate tile: 0=i,1=f,2=g,3=o (base nj*256)
  const int q    = lane >> 4;   // quad
  const int u    = lane & 15;   // frag row/col within 16-tile
  const int em   = tid >> 4;    // elementwise chain (0..31)
  const int eu   = tid & 15;    // elementwise unit within WG slice (0..15)

  // Opaque zero: an SGPR the compiler cannot constant-fold.
  int zz;
  asm volatile("s_mov_b32 %0, 0" : "=s"(zz));

  // ---- derive (group g, member w) from the physical XCD id ----
  // 512 blocks => 64 slots/XCD => 4 groups/XCD (16 WGs each). Slots i and
  // i+32 land on one CU (round-robin) and differ in group => antiphase.
  __shared__ int s_gw[2];
  if (tid == 0) {
    uint32_t xcc;
    asm volatile("s_getreg_b32 %0, hwreg(HW_REG_XCC_ID)" : "=s"(xcc));
    xcc &= 7;
    const int slot = atomicAdd((int*)(ws + WS_SLOT_OFF) + (size_t)xcc * 32, 1);  // device-scope, once
    s_gw[0] = (int)xcc * 4 + (slot >> 4);   // group 0..31 (4 per XCD)
    s_gw[1] = slot & 15;                    // member 0..15 (16-unit slice)
  }
  __syncthreads();
  const int g = s_gw[0];
  const int w = s_gw[1];

  int* ctr = (int*)(ws + (size_t)g * 128);   // g<32 => 0..4095, below WS_SLOT_OFF
  _Float16* h0b = (_Float16*)(ws + WS_HBUF_OFF + (size_t)g * GROUP_WS_BYTES);
  _Float16* h1b = h0b + HBUF_ELEMS;

  __shared__ __align__(16) _Float16 sb0[HBUF_ELEMS];    // staged h0 (16KB)
  __shared__ __align__(16) _Float16 sb1[HBUF_ELEMS];    // staged h1 (16KB)
  __shared__ __align__(16) _Float16 wfcs[32 * 65 * 8];  // Wfc chunked, padded (33.3KB)
  __shared__ __align__(16) _Float16 xbuf[32 * 72];      // feedback x (4.5KB, bank pad)
  __shared__ __align__(16) float    xpbuf[2176];        // UNION: exch[4][32][17] / predbuf[32][65]
  float* exch    = xpbuf;   // used L0/L1 gate scatter -> elementwise
  float* predbuf = xpbuf;   // used FC -> softmax (barrier-separated from exch)

  // ---------------- weight fragments (register-resident, f16) ----------------
  // gates = act @ W^T. B-frag: n(row)=u, k=q*8+j. One gate tile per wave.
  half8 bL0[10]; half8 bL1[16];
  float biasL0, biasL1, biasFC;
  {
    const int row = nj * 256 + w * 16 + u;   // torch gate order i,f,g,o
    biasL0 = bih0[row] + bhh0[row];
    biasL1 = bih1[row] + bhh1[row];
    #pragma unroll
    for (int kt = 0; kt < 10; ++kt) {   // L0: K = 64(x) + 256(h0)
      const int k0 = kt * 32 + q * 8;
      const float* src = (kt < 2) ? (Wih0 + (size_t)row * 64 + k0)
                                  : (Whh0 + (size_t)row * 256 + (k0 - 64));
      half8 v;
      #pragma unroll
      for (int j = 0; j < 8; ++j) v[j] = (_Float16)src[j];
      bL0[kt] = v;
    }
    #pragma unroll
    for (int kt = 0; kt < 16; ++kt) {   // L1: K = 256(h0new) + 256(h1)
      const int k0 = kt * 32 + q * 8;
      const float* src = (kt < 8) ? (Wih1 + (size_t)row * 256 + k0)
                                  : (Whh1 + (size_t)row * 256 + (k0 - 256));
      half8 v;
      #pragma unroll
      for (int j = 0; j < 8; ++j) v[j] = (_Float16)src[j];
      bL1[kt] = v;
    }
    biasFC = bfc[nj * 16 + u];          // FC row for this wave's tile
  }
  // Wfc -> LDS, chunk-padded: frag (c,rowF) at (c*65 + rowF)*8, c = k/8.
  for (int i = tid; i < 2048; i += NTHR) {
    const int rowF = i & 63;
    const int c    = i >> 6;
    const float* s = Wfc + (size_t)rowF * 256 + c * 8;
    half8 v;
    #pragma unroll
    for (int j = 0; j < 8; ++j) v[j] = (_Float16)s[j];
    *(half8*)(wfcs + (size_t)(c * 65 + rowF) * 8) = v;
  }

  // ---------------- state init (elementwise: chain em, unit w*16+eu) ----------
  float c0st, c1st, h0sv = 0.0f, h1sv = 0.0f;
  {
    const size_t idx = (size_t)(g * 32 + em) * 256 + w * 16 + eu;
    c0st = c0in[idx];
    c1st = c0in[262144 + idx];
  }
  // initial h -> chunked L2 buffers (own chunks c = 2w, 2w+1)
  if (tid < 64) {
    const int m  = tid & 31;
    const int cc = tid >> 5;            // 0..1
    const int c  = w * 2 + cc;
    #pragma unroll
    for (int l = 0; l < 2; ++l) {
      const float* s = h0in + (size_t)l * 262144 + (size_t)(g * 32 + m) * 256 + c * 8;
      half8 pk;
      #pragma unroll
      for (int j = 0; j < 8; ++j) pk[j] = (_Float16)s[j];
      *(half8*)((l ? h1b : h0b) + (size_t)(c * 32 + m) * 8) = pk;
    }
  }
  for (int i = tid; i < 32 * 64; i += NTHR) {  // x0 = zeros, col 61 (= INPUT_SIZE-3) = 1
    const int row = i >> 6, col = i & 63;
    xbuf[row * 72 + col] = (col == 61) ? (_Float16)1.0f : (_Float16)0.0f;
  }

  int phase = 0;
  group_barrier(ctr, &phase, zz);      // initial h visible group-wide

  stage16k8(h0b, sb0, tid);            // sb0 <- h0(init)
  stage16k8(h1b, sb1, tid);            // sb1 <- h1(init)
  __syncthreads();                     // drain staging

  // ---------------- time loop ----------------
  for (int t = 0; t < TSTEPS; ++t) {
    // ======== Layer 0: gates = [x | h0_prev] @ W^T (xbuf + sb0, all LDS) ========
    {
      f32x4 acc;
      acc[0] = biasL0; acc[1] = biasL0; acc[2] = biasL0; acc[3] = biasL0;
      const int m_ = mi * 16 + u;
      #pragma unroll
      for (int kt = 0; kt < 10; ++kt) {
        half8 a;
        if (kt < 2) a = *(const half8*)(xbuf + m_ * 72 + kt * 32 + q * 8);
        else        a = *(const half8*)(sb0 + (size_t)((kt * 4 - 8 + q) * 32 + m_) * 8);
        acc = __builtin_amdgcn_mfma_f32_16x16x32_f16(a, bL0[kt], acc, 0, 0, 0);
      }
      #pragma unroll
      for (int r = 0; r < 4; ++r)
        exch[(nj * 32 + mi * 16 + q * 4 + r) * 17 + u] = acc[r];
    }
    __syncthreads();
    {  // elementwise L0 (512 threads x 1 entry)
      const float iv = exch[(0 * 32 + em) * 17 + eu];
      const float fv = exch[(1 * 32 + em) * 17 + eu];
      const float gv = exch[(2 * 32 + em) * 17 + eu];
      const float ov = exch[(3 * 32 + em) * 17 + eu];
      const float cn = sigm(fv) * c0st + sigm(iv) * tanh_f(gv);
      c0st = cn;
      const float hh = sigm(ov) * tanh_f(cn);
      h0sv = hh;
      const float other = __shfl_xor(hh, 1);
      if (!(eu & 1)) {
        union { _Float16 h[2]; uint32_t u32; } pk;
        pk.h[0] = (_Float16)hh; pk.h[1] = (_Float16)other;
        ((uint32_t*)h0b)[(uint32_t)((w * 2 + (eu >> 3)) * 32 + em) * 4 + ((eu & 7) >> 1)] = pk.u32;
      }
    }
    group_barrier(ctr, &phase, zz);    // b1: h0(t) visible group-wide

    stage16k8(h0b, sb0, tid);          // sb0 <- h0(t); drained by sync below

    // ======== Layer 1: gates = [h0_new | h1_prev] @ W^T ========
    {
      f32x4 acc;
      acc[0] = biasL1; acc[1] = biasL1; acc[2] = biasL1; acc[3] = biasL1;
      const int m_ = mi * 16 + u;
      // h1_prev half from sb1 (staged after b2(t-1), long drained)
      #pragma unroll
      for (int kt = 8; kt < 16; ++kt) {
        const half8 a = *(const half8*)(sb1 + (size_t)(((kt - 8) * 4 + q) * 32 + m_) * 8);
        acc = __builtin_amdgcn_mfma_f32_16x16x32_f16(a, bL1[kt], acc, 0, 0, 0);
      }
      __syncthreads();   // drain sb0 staging (all waves)
      // h0_new half from sb0
      #pragma unroll
      for (int kt = 0; kt < 8; ++kt) {
        const half8 a = *(const half8*)(sb0 + (size_t)((kt * 4 + q) * 32 + m_) * 8);
        acc = __builtin_amdgcn_mfma_f32_16x16x32_f16(a, bL1[kt], acc, 0, 0, 0);
      }
      #pragma unroll
      for (int r = 0; r < 4; ++r)
        exch[(nj * 32 + mi * 16 + q * 4 + r) * 17 + u] = acc[r];
    }
    __syncthreads();
    {  // elementwise L1
      const float iv = exch[(0 * 32 + em) * 17 + eu];
      const float fv = exch[(1 * 32 + em) * 17 + eu];
      const float gv = exch[(2 * 32 + em) * 17 + eu];
      const float ov = exch[(3 * 32 + em) * 17 + eu];
      const float cn = sigm(fv) * c1st + sigm(iv) * tanh_f(gv);
      c1st = cn;
      const float hh = sigm(ov) * tanh_f(cn);
      h1sv = hh;
      const float other = __shfl_xor(hh, 1);
      if (!(eu & 1)) {
        union { _Float16 h[2]; uint32_t u32; } pk;
        pk.h[0] = (_Float16)hh; pk.h[1] = (_Float16)other;
        ((uint32_t*)h1b)[(uint32_t)((w * 2 + (eu >> 3)) * 32 + em) * 4 + ((eu & 7) >> 1)] = pk.u32;
      }
    }
    group_barrier(ctr, &phase, zz);    // b2: h1(t) visible group-wide

    stage16k8(h1b, sb1, tid);          // sb1 <- h1(t); serves L1(t+1)

    // ======== FC (redundant per WG): A from h1b (L2), B from wfcs ========
    {
      f32x4 accF;
      accF[0] = biasFC; accF[1] = biasFC; accF[2] = biasFC; accF[3] = biasFC;
      const int m_ = mi * 16 + u;
      #pragma unroll
      for (int kt = 0; kt < 8; ++kt) {
        const half8 b = *(const half8*)(wfcs + (size_t)((kt * 4 + q) * 65 + nj * 16 + u) * 8);
        const half8 a = ld_frag(h1b, (kt * 4 + q) * 32 + m_);
        accF = __builtin_amdgcn_mfma_f32_16x16x32_f16(a, b, accF, 0, 0, 0);
      }
      #pragma unroll
      for (int r = 0; r < 4; ++r)
        predbuf[(mi * 16 + q * 4 + r) * 65 + nj * 16 + u] = accF[r];
    }
    __syncthreads();   // also drains sb1 staging
    {  // softmax + out + feedback (512 threads: 4 cols each)
      const int row = tid >> 4;   // group-local chain (0..31)
      const int cg  = tid & 15;   // 4-col group
      const float* pr = predbuf + row * 65 + cg * 4;
      float p[4];
      #pragma unroll
      for (int j = 0; j < 4; ++j) p[j] = pr[j];
      float mx = -3.0e38f;
      #pragma unroll
      for (int j = 0; j < 4; ++j)
        if (!(cg == 15 && j == 3)) mx = fmaxf(mx, p[j]);   // exclude col 63 (dur)
      mx = fmaxf(mx, __shfl_xor(mx, 1));
      mx = fmaxf(mx, __shfl_xor(mx, 2));
      mx = fmaxf(mx, __shfl_xor(mx, 4));
      mx = fmaxf(mx, __shfl_xor(mx, 8));
      float sm = 0.0f;
      #pragma unroll
      for (int j = 0; j < 4; ++j)
        if (!(cg == 15 && j == 3)) sm += __expf(p[j] - mx);
      sm += __shfl_xor(sm, 1);
      sm += __shfl_xor(sm, 2);
      sm += __shfl_xor(sm, 4);
      sm += __shfl_xor(sm, 8);
      const float lz = mx + __logf(sm);
      float o[4];
      #pragma unroll
      for (int j = 0; j < 4; ++j) o[j] = p[j] - lz;
      if (cg == 15) o[3] = sigm(p[3]);                     // duration = sigmoid(pred[63])
      _Float16* xw = xbuf + row * 72 + cg * 4;             // feedback x = out (f16)
      #pragma unroll
      for (int j = 0; j < 4; ++j) xw[j] = (_Float16)o[j];
      if ((row >> 1) == w) {                               // each WG writes 2 of 32 rows
        const int ch = g * 32 + row;
        float* dst = out + ((size_t)ch * TSTEPS + t) * 64 + cg * 4;
        #pragma unroll
        for (int j = 0; j < 4; ++j) dst[j] = o[j];
      }
    }
    __syncthreads();
  }

  // ---------------- final h_f, c_f (elementwise ownership) ----------------
  {
    float* hfp = out + OUT_ELEMS;
    float* cfp = out + OUT_ELEMS + HF_ELEMS;
    const size_t idx = (size_t)(g * 32 + em) * 256 + w * 16 + eu;
    hfp[idx]          = h0sv;
    hfp[262144 + idx] = h1sv;
    cfp[idx]          = c0st;
    cfp[262144 + idx] = c1st;
  }
}

extern "C" void kernel_launch(void* const* d_in, const int* in_sizes, int n_in,
                              void* d_out, int out_size, void* d_ws, size_t ws_size,
                              hipStream_t stream) {
  (void)in_sizes; (void)n_in; (void)out_size;
  if (ws_size < (size_t)WS_NEEDED) return;

  const float* h0   = (const float*)d_in[1];
  const float* c0   = (const float*)d_in[2];
  const float* Wih0 = (const float*)d_in[3];
  const float* Whh0 = (const float*)d_in[4];
  const float* bih0 = (const float*)d_in[5];
  const float* bhh0 = (const float*)d_in[6];
  const float* Wih1 = (const float*)d_in[7];
  const float* Whh1 = (const float*)d_in[8];
  const float* bih1 = (const float*)d_in[9];
  const float* bhh1 = (const float*)d_in[10];
  const float* Wfc  = (const float*)d_in[11];
  const float* bfc  = (const float*)d_in[12];
  float* outp = (float*)d_out;
  char*  wsp  = (char*)d_ws;

  // zero barrier + slot counters (ws is re-poisoned to 0xAA before every
  // launch; end-of-dispatch flush of the memset makes zeros globally visible)
  hipMemsetAsync(d_ws, 0, WS_HBUF_OFF, stream);

  void* args[] = { &h0, &c0, &Wih0, &Whh0, &bih0, &bhh0, &Wih1, &Whh1,
                   &bih1, &bhh1, &Wfc, &bfc, &outp, &wsp };
  hipError_t e = hipLaunchCooperativeKernel((const void*)decoder_kernel,
                                            dim3(NGROUP * GWG), dim3(NTHR),
                                            args, 0u, stream);
  if (e != hipSuccess) {
    // fallback: plain launch (512 blocks at 2/CU are co-resident)
    decoder_kernel<<<dim3(NGROUP * GWG), dim3(NTHR), 0, stream>>>(
        h0, c0, Wih0, Whh0, bih0, bhh0, Wih1, Whh1, bih1, bhh1, Wfc, bfc, outp, wsp);
  }
}

// Round 10
// 3511.935 us; speedup vs baseline: 2.1815x; 2.1815x over previous
//
#include <hip/hip_runtime.h>
#include <stdint.h>
#include <stddef.h>

// Persistent 2-layer LSTM decoder, B=1024, H=256, T=512.
//
// R14: VIRTUAL BLOCKS. R12 (8-wave block, 2 waves/SIMD) = 3340us best; its
// idle is correlated: all 8 waves share every __syncthreads/barrier. R13
// proved decorrelated co-residency works (occ 47%) but 4 waves/SIMD caps
// unified regs at 128 -> weights spill (VGPR=64, 15.8GB scratch). So:
// decorrelate WITHIN one block at 2 waves/SIMD:
//  - 512-thr block = 2 virtual blocks (VB) of 4 waves. VB-A: waves 0-3,
//    VB-B: waves 4-7, DIFFERENT groups (32 groups x 32 chains x 16 VBs).
//    Wave->SIMD round-robin puts one A + one B wave per SIMD; A's barrier/
//    drain stalls are covered by B's compute and vice versa.
//  - NO __syncthreads in the time loop. VB-local sync = LDS-atomic barrier:
//    per-wave s_waitcnt vmcnt(0) lgkmcnt(0) drain, lane0 ds_add arrive +
//    ds_read poll (s_sleep backoff). Group barrier = proven XCD-L2 RMW
//    (R4-R12) executed by VB wave0-lane0 only; completion fanned out via an
//    LDS done-flag (avoids R9's poller pileup; no sc0-load polls - R8/R10).
//  - Geometry per VB: 4 waves, wave nj = gate tile (i/f/g/o), M=32 chains
//    (2 mt tiles). Weights/wave 104 VGPR (R12 layout). Wfc in LDS, SHARED
//    by both VBs (read-only). sb0/sb1 16KB per VB. exch/predbuf unioned.
//    LDS ~124KB -> 1 block/CU, 2 waves/SIMD, 256-reg budget (R12: 124).
//  - Race-freedom = R12 argument: stage reads of h(t) complete before our
//    group-arrive; cross-WG writes of h(t+1) happen only post-wait.
//
// h-buffer layout (per group, per layer): chunked f16
//   f16_index = (c*32 + m)*8 + e, c = unit/8 (0..31), m = chain (0..31),
//   e = unit%8. A-fragment = one 16B chunk; chunk c = contiguous 512B.

#define NGROUP 32
#define VBWG   16     // member VBs per group
#define NTHR   512
#define NBLK   256
#define TSTEPS 512

typedef _Float16 half8 __attribute__((ext_vector_type(8)));
typedef float    f32x4 __attribute__((ext_vector_type(4)));

#define OUT_ELEMS   33554432   // 1024*512*64
#define HF_ELEMS    524288     // 2*1024*256
#define HBUF_ELEMS  8192       // 32*256 (f16) per layer (16KB)
#define GROUP_WS_BYTES 32768   // 2 layers * 16KB
#define WS_SLOT_OFF 4096       // ctrs live in 0..4095 (32 groups * 128B)
#define WS_HBUF_OFF 8192
#define WS_NEEDED   (WS_HBUF_OFF + NGROUP * GROUP_WS_BYTES)

__device__ __forceinline__ float sigm(float x)   { return 1.0f / (1.0f + __expf(-x)); }
__device__ __forceinline__ float tanh_f(float x) { return 1.0f - 2.0f / (__expf(2.0f * x) + 1.0f); }

// ---- VB-local 4-wave barrier (LDS). Entry drain: vmcnt(0) (global stores
// to write-through L1 are in XCD L2; staging loads complete) + lgkmcnt(0)
// (LDS writes visible). lane0 arrives (ds_add) and polls (ds_read);
// exec-masked loop stalls the whole wave. Exit lgkmcnt(0)+clobber orders
// subsequent LDS reads. ----
__device__ __forceinline__ void vb_bar(int* vbctr, int* vbph, int lane) {
  asm volatile("s_waitcnt vmcnt(0) lgkmcnt(0)" ::: "memory");
  const int target = 4 * (++(*vbph));
  if (lane == 0) {
    __hip_atomic_fetch_add(vbctr, 1, __ATOMIC_RELEASE, __HIP_MEMORY_SCOPE_WORKGROUP);
    while (__hip_atomic_load(vbctr, __ATOMIC_RELAXED, __HIP_MEMORY_SCOPE_WORKGROUP) < target)
      __builtin_amdgcn_s_sleep(1);
  }
  asm volatile("s_waitcnt lgkmcnt(0)" ::: "memory");
}

// ---- Group barrier, per-VB (16 VBs across 16 blocks, one XCD). Local
// vb_bar first (all 4 waves drained+arrived). Then VB wave0-lane0: global
// RMW arrive + RMW poll (R4-R12 proven; zz defeats the add-0 fold) +
// buffer_inv sc0 acquire (CU-wide L1 invalidate) + LDS done-flag store.
// Other waves poll the LDS flag. ----
__device__ __forceinline__ void group_bar(int* ctr, int* gph, int zz,
                                          int* vbctr, int* vbph, int* vbdone,
                                          int wv, int lane) {
  vb_bar(vbctr, vbph, lane);
  const int ep = ++(*gph);
  if (wv == 0 && lane == 0) {
    __hip_atomic_fetch_add(ctr, 1, __ATOMIC_RELEASE, __HIP_MEMORY_SCOPE_WORKGROUP);
    const int target = VBWG * ep;
    while (__hip_atomic_fetch_add(ctr, zz, __ATOMIC_RELAXED, __HIP_MEMORY_SCOPE_WORKGROUP) < target)
      __builtin_amdgcn_s_sleep(1);
    asm volatile("buffer_inv sc0" ::: "memory");   // L1-only invalidate (gfx940+)
    __hip_atomic_store(vbdone, ep, __ATOMIC_RELEASE, __HIP_MEMORY_SCOPE_WORKGROUP);
  }
  if (lane == 0) {
    while (__hip_atomic_load(vbdone, __ATOMIC_RELAXED, __HIP_MEMORY_SCOPE_WORKGROUP) < ep)
      __builtin_amdgcn_s_sleep(1);
  }
  asm volatile("s_waitcnt lgkmcnt(0)" ::: "memory");
}

// 16B A-fragment plain load from a chunked h-buffer in L2.
__device__ __forceinline__ half8 ld_frag(const _Float16* buf, int idx16) {
  return *(const half8*)(buf + (size_t)idx16 * 8);
}

// 16KB linear global->LDS copy by a VB's 4 waves (4 insts/wave), zero VGPR
// dest. LDS dest = wave-uniform base + lane*16 (m97/m104 semantics).
__device__ __forceinline__ void stage16k4(const void* src, void* lds_dst,
                                          int wv, int lane) {
  const char* s = (const char*)src + lane * 16;
  char* d = (char*)lds_dst;
  #pragma unroll
  for (int i = 0; i < 4; ++i) {
    const int off = (i * 4 + wv) * 1024;
    __builtin_amdgcn_global_load_lds(
        (const __attribute__((address_space(1))) void*)(s + off),
        (__attribute__((address_space(3))) void*)(d + off),
        16, 0, 0);
  }
}

__global__ __launch_bounds__(NTHR, 2)
void decoder_kernel(const float* __restrict__ h0in, const float* __restrict__ c0in,
                    const float* __restrict__ Wih0, const float* __restrict__ Whh0,
                    const float* __restrict__ bih0, const float* __restrict__ bhh0,
                    const float* __restrict__ Wih1, const float* __restrict__ Whh1,
                    const float* __restrict__ bih1, const float* __restrict__ bhh1,
                    const float* __restrict__ Wfc,  const float* __restrict__ bfc,
                    float* __restrict__ out, char* __restrict__ ws)
{
  const int tid  = threadIdx.x;
  const int lane = tid & 63;
  const int vb   = tid >> 8;        // virtual block 0/1
  const int vtid = tid & 255;       // thread within VB
  const int wv   = vtid >> 6;       // wave within VB (0..3)
  const int nj   = wv;              // gate tile: 0=i,1=f,2=g,3=o
  const int q    = lane >> 4;       // quad
  const int u    = lane & 15;       // frag row/col in 16-tile
  const int em   = vtid >> 3;       // elementwise chain (0..31)
  const int eu2  = (vtid & 7) * 2;  // elementwise unit pair (0,2,..,14)

  // Opaque zero: an SGPR the compiler cannot constant-fold.
  int zz;
  asm volatile("s_mov_b32 %0, 0" : "=s"(zz));

  // ---- derive (groups gA/gB, member w) from the physical XCD id ----
  // 256 blocks => 32 slots/XCD => 4 groups/XCD (16 VBs each). Block's VB-A
  // and VB-B get adjacent groups; their schedules free-run (antiphase).
  __shared__ int s_gw[2];
  __shared__ int vbctr[2], vbdone[2];
  if (tid == 0) {
    uint32_t xcc;
    asm volatile("s_getreg_b32 %0, hwreg(HW_REG_XCC_ID)" : "=s"(xcc));
    xcc &= 7;
    const int slot = atomicAdd((int*)(ws + WS_SLOT_OFF) + (size_t)xcc * 32, 1);  // device-scope, once
    s_gw[0] = (int)xcc * 4 + (slot >> 4) * 2;   // VB-A group
    s_gw[1] = slot & 15;                        // member 0..15
  }
  if (tid < 2) { vbctr[tid] = 0; vbdone[tid] = 0; }
  __syncthreads();
  const int g = s_gw[0] + vb;       // this VB's group
  const int w = s_gw[1];

  int* ctr = (int*)(ws + (size_t)g * 128);   // g<32 => below WS_SLOT_OFF
  _Float16* h0b = (_Float16*)(ws + WS_HBUF_OFF + (size_t)g * GROUP_WS_BYTES);
  _Float16* h1b = h0b + HBUF_ELEMS;

  __shared__ __align__(16) _Float16 sb0[2][HBUF_ELEMS];   // staged h0 per VB (16KB ea)
  __shared__ __align__(16) _Float16 sb1[2][HBUF_ELEMS];   // staged h1 per VB
  __shared__ __align__(16) _Float16 wfcs[32 * 65 * 8];    // Wfc chunk-padded (33.3KB, shared)
  __shared__ __align__(16) _Float16 xbuf[2][32 * 72];     // feedback x per VB (4.5KB ea)
  __shared__ __align__(16) float    xpbuf[2][2176];       // UNION exch[4][32][17] / predbuf[32][65]

  float* exch    = xpbuf[vb];
  float* predbuf = xpbuf[vb];

  // ---------------- weight fragments (register-resident, f16) ----------------
  // gates = act @ W^T. B-frag: n(row)=u, k=q*8+j. One gate tile per wave.
  half8 bL0[10]; half8 bL1[16];
  float biasL0, biasL1, biasFC;
  {
    const int row = nj * 256 + w * 16 + u;   // torch gate order i,f,g,o
    biasL0 = bih0[row] + bhh0[row];
    biasL1 = bih1[row] + bhh1[row];
    #pragma unroll
    for (int kt = 0; kt < 10; ++kt) {   // L0: K = 64(x) + 256(h0)
      const int k0 = kt * 32 + q * 8;
      const float* src = (kt < 2) ? (Wih0 + (size_t)row * 64 + k0)
                                  : (Whh0 + (size_t)row * 256 + (k0 - 64));
      half8 v;
      #pragma unroll
      for (int j = 0; j < 8; ++j) v[j] = (_Float16)src[j];
      bL0[kt] = v;
    }
    #pragma unroll
    for (int kt = 0; kt < 16; ++kt) {   // L1: K = 256(h0new) + 256(h1)
      const int k0 = kt * 32 + q * 8;
      const float* src = (kt < 8) ? (Wih1 + (size_t)row * 256 + k0)
                                  : (Whh1 + (size_t)row * 256 + (k0 - 256));
      half8 v;
      #pragma unroll
      for (int j = 0; j < 8; ++j) v[j] = (_Float16)src[j];
      bL1[kt] = v;
    }
    biasFC = bfc[nj * 16 + u];
  }
  // Wfc -> LDS (shared, identical content; all 512 threads cooperate).
  for (int i = tid; i < 2048; i += NTHR) {
    const int rowF = i & 63;
    const int c    = i >> 6;
    const float* s = Wfc + (size_t)rowF * 256 + c * 8;
    half8 v;
    #pragma unroll
    for (int j = 0; j < 8; ++j) v[j] = (_Float16)s[j];
    *(half8*)(wfcs + (size_t)(c * 65 + rowF) * 8) = v;
  }

  // ---------------- state init (elementwise: chain em, units eu2,eu2+1) ------
  float c0st[2], c1st[2], h0sv[2], h1sv[2];
  #pragma unroll
  for (int e = 0; e < 2; ++e) {
    const size_t idx = (size_t)(g * 32 + em) * 256 + w * 16 + eu2 + e;
    c0st[e] = c0in[idx];
    c1st[e] = c0in[262144 + idx];
    h0sv[e] = 0.0f; h1sv[e] = 0.0f;
  }
  // initial h -> this VB's chunked L2 buffers (own chunks c = 2w, 2w+1)
  if (vtid < 64) {
    const int m  = vtid & 31;
    const int cc = vtid >> 5;
    const int c  = w * 2 + cc;
    #pragma unroll
    for (int l = 0; l < 2; ++l) {
      const float* s = h0in + (size_t)l * 262144 + (size_t)(g * 32 + m) * 256 + c * 8;
      half8 pk;
      #pragma unroll
      for (int j = 0; j < 8; ++j) pk[j] = (_Float16)s[j];
      *(half8*)((l ? h1b : h0b) + (size_t)(c * 32 + m) * 8) = pk;
    }
  }
  for (int i = vtid; i < 32 * 64; i += 256) {  // x0 = zeros, col 61 (= INPUT_SIZE-3) = 1
    const int row = i >> 6, col = i & 63;
    xbuf[vb][row * 72 + col] = (col == 61) ? (_Float16)1.0f : (_Float16)0.0f;
  }

  int vbph = 0, gph = 0;
  int* myctr  = &vbctr[vb];
  int* mydone = &vbdone[vb];
  __syncthreads();                             // last block-wide sync
  group_bar(ctr, &gph, zz, myctr, &vbph, mydone, wv, lane);  // init h visible

  stage16k4(h0b, sb0[vb], wv, lane);
  stage16k4(h1b, sb1[vb], wv, lane);
  vb_bar(myctr, &vbph, lane);                  // drain staging

  // ---------------- time loop (per VB, fully independent) ----------------
  for (int t = 0; t < TSTEPS; ++t) {
    // ======== L0 MFMA: gates = [x | h0_prev] @ W^T (xbuf + sb0) ========
    {
      f32x4 acc[2];
      #pragma unroll
      for (int mt = 0; mt < 2; ++mt) {
        f32x4 v; v[0] = biasL0; v[1] = biasL0; v[2] = biasL0; v[3] = biasL0;
        acc[mt] = v;
      }
      #pragma unroll
      for (int kt = 0; kt < 10; ++kt) {
        #pragma unroll
        for (int mt = 0; mt < 2; ++mt) {
          const int m = mt * 16 + u;
          half8 a;
          if (kt < 2) a = *(const half8*)(xbuf[vb] + m * 72 + kt * 32 + q * 8);
          else        a = *(const half8*)(sb0[vb] + (size_t)((kt * 4 - 8 + q) * 32 + m) * 8);
          acc[mt] = __builtin_amdgcn_mfma_f32_16x16x32_f16(a, bL0[kt], acc[mt], 0, 0, 0);
        }
      }
      #pragma unroll
      for (int mt = 0; mt < 2; ++mt)
        #pragma unroll
        for (int r = 0; r < 4; ++r)
          exch[(nj * 32 + mt * 16 + q * 4 + r) * 17 + u] = acc[mt][r];
    }
    vb_bar(myctr, &vbph, lane);
    {  // elementwise L0 (256 threads x 2 entries)
      float hv[2];
      #pragma unroll
      for (int e = 0; e < 2; ++e) {
        const int ec = eu2 + e;
        const float iv = exch[(0 * 32 + em) * 17 + ec];
        const float fv = exch[(1 * 32 + em) * 17 + ec];
        const float gv = exch[(2 * 32 + em) * 17 + ec];
        const float ov = exch[(3 * 32 + em) * 17 + ec];
        const float cn = sigm(fv) * c0st[e] + sigm(iv) * tanh_f(gv);
        c0st[e] = cn;
        const float hh = sigm(ov) * tanh_f(cn);
        h0sv[e] = hh; hv[e] = hh;
      }
      union { _Float16 h[2]; uint32_t u32; } pk;
      pk.h[0] = (_Float16)hv[0]; pk.h[1] = (_Float16)hv[1];
      ((uint32_t*)h0b)[(uint32_t)((w * 2 + (eu2 >> 3)) * 32 + em) * 4 + ((eu2 & 7) >> 1)] = pk.u32;
    }
    group_bar(ctr, &gph, zz, myctr, &vbph, mydone, wv, lane);   // b1

    stage16k4(h0b, sb0[vb], wv, lane);         // sb0 <- h0(t)

    // ======== L1 MFMA: gates = [h0_new | h1_prev] @ W^T ========
    {
      f32x4 acc[2];
      #pragma unroll
      for (int mt = 0; mt < 2; ++mt) {
        f32x4 v; v[0] = biasL1; v[1] = biasL1; v[2] = biasL1; v[3] = biasL1;
        acc[mt] = v;
      }
      // h1_prev half from sb1 (staged post-b2(t-1), drained)
      #pragma unroll
      for (int kt = 8; kt < 16; ++kt) {
        #pragma unroll
        for (int mt = 0; mt < 2; ++mt) {
          const int m = mt * 16 + u;
          const half8 a = *(const half8*)(sb1[vb] + (size_t)(((kt - 8) * 4 + q) * 32 + m) * 8);
          acc[mt] = __builtin_amdgcn_mfma_f32_16x16x32_f16(a, bL1[kt], acc[mt], 0, 0, 0);
        }
      }
      vb_bar(myctr, &vbph, lane);              // drain sb0 staging (4 waves)
      // h0_new half from sb0
      #pragma unroll
      for (int kt = 0; kt < 8; ++kt) {
        #pragma unroll
        for (int mt = 0; mt < 2; ++mt) {
          const int m = mt * 16 + u;
          const half8 a = *(const half8*)(sb0[vb] + (size_t)((kt * 4 + q) * 32 + m) * 8);
          acc[mt] = __builtin_amdgcn_mfma_f32_16x16x32_f16(a, bL1[kt], acc[mt], 0, 0, 0);
        }
      }
      #pragma unroll
      for (int mt = 0; mt < 2; ++mt)
        #pragma unroll
        for (int r = 0; r < 4; ++r)
          exch[(nj * 32 + mt * 16 + q * 4 + r) * 17 + u] = acc[mt][r];
    }
    vb_bar(myctr, &vbph, lane);
    {  // elementwise L1
      float hv[2];
      #pragma unroll
      for (int e = 0; e < 2; ++e) {
        const int ec = eu2 + e;
        const float iv = exch[(0 * 32 + em) * 17 + ec];
        const float fv = exch[(1 * 32 + em) * 17 + ec];
        const float gv = exch[(2 * 32 + em) * 17 + ec];
        const float ov = exch[(3 * 32 + em) * 17 + ec];
        const float cn = sigm(fv) * c1st[e] + sigm(iv) * tanh_f(gv);
        c1st[e] = cn;
        const float hh = sigm(ov) * tanh_f(cn);
        h1sv[e] = hh; hv[e] = hh;
      }
      union { _Float16 h[2]; uint32_t u32; } pk;
      pk.h[0] = (_Float16)hv[0]; pk.h[1] = (_Float16)hv[1];
      ((uint32_t*)h1b)[(uint32_t)((w * 2 + (eu2 >> 3)) * 32 + em) * 4 + ((eu2 & 7) >> 1)] = pk.u32;
    }
    group_bar(ctr, &gph, zz, myctr, &vbph, mydone, wv, lane);   // b2

    stage16k4(h1b, sb1[vb], wv, lane);         // sb1 <- h1(t), for L1(t+1)

    // ======== FC: A from h1b (L2, fresh post-b2), B from wfcs ========
    {
      f32x4 accF[2];
      #pragma unroll
      for (int mt = 0; mt < 2; ++mt) {
        f32x4 v; v[0] = biasFC; v[1] = biasFC; v[2] = biasFC; v[3] = biasFC;
        accF[mt] = v;
      }
      #pragma unroll
      for (int kt = 0; kt < 8; ++kt) {
        const half8 b = *(const half8*)(wfcs + (size_t)((kt * 4 + q) * 65 + nj * 16 + u) * 8);
        #pragma unroll
        for (int mt = 0; mt < 2; ++mt) {
          const half8 a = ld_frag(h1b, (kt * 4 + q) * 32 + mt * 16 + u);
          accF[mt] = __builtin_amdgcn_mfma_f32_16x16x32_f16(a, b, accF[mt], 0, 0, 0);
        }
      }
      #pragma unroll
      for (int mt = 0; mt < 2; ++mt)
        #pragma unroll
        for (int r = 0; r < 4; ++r)
          predbuf[(mt * 16 + q * 4 + r) * 65 + nj * 16 + u] = accF[mt][r];
    }
    vb_bar(myctr, &vbph, lane);                // drains sb1 staging + FC loads
    {  // softmax + out + feedback (256 threads: 8 cols each)
      const int row = vtid >> 3;   // group-local chain (0..31)
      const int cg  = vtid & 7;    // 8-col group
      const float* pr = predbuf + row * 65 + cg * 8;
      float p[8];
      #pragma unroll
      for (int j = 0; j < 8; ++j) p[j] = pr[j];
      float mx = -3.0e38f;
      #pragma unroll
      for (int j = 0; j < 8; ++j)
        if (!(cg == 7 && j == 7)) mx = fmaxf(mx, p[j]);   // exclude col 63 (dur)
      mx = fmaxf(mx, __shfl_xor(mx, 1));
      mx = fmaxf(mx, __shfl_xor(mx, 2));
      mx = fmaxf(mx, __shfl_xor(mx, 4));
      float sm = 0.0f;
      #pragma unroll
      for (int j = 0; j < 8; ++j)
        if (!(cg == 7 && j == 7)) sm += __expf(p[j] - mx);
      sm += __shfl_xor(sm, 1);
      sm += __shfl_xor(sm, 2);
      sm += __shfl_xor(sm, 4);
      const float lz = mx + __logf(sm);
      float o[8];
      #pragma unroll
      for (int j = 0; j < 8; ++j) o[j] = p[j] - lz;
      if (cg == 7) o[7] = sigm(p[7]);                      // duration = sigmoid(pred[63])
      _Float16* xw = xbuf[vb] + row * 72 + cg * 8;         // feedback x = out (f16)
      #pragma unroll
      for (int j = 0; j < 8; ++j) xw[j] = (_Float16)o[j];
      if ((row >> 1) == w) {                               // each VB writes 2 of 32 rows
        const int ch = g * 32 + row;
        float* dst = out + ((size_t)ch * TSTEPS + t) * 64 + cg * 8;
        #pragma unroll
        for (int j = 0; j < 8; ++j) dst[j] = o[j];
      }
    }
    vb_bar(myctr, &vbph, lane);                // xbuf ready for next L0
  }

  // ---------------- final h_f, c_f (elementwise ownership) ----------------
  {
    float* hfp = out + OUT_ELEMS;
    float* cfp = out + OUT_ELEMS + HF_ELEMS;
    #pragma unroll
    for (int e = 0; e < 2; ++e) {
      const size_t idx = (size_t)(g * 32 + em) * 256 + w * 16 + eu2 + e;
      hfp[idx]          = h0sv[e];
      hfp[262144 + idx] = h1sv[e];
      cfp[idx]          = c0st[e];
      cfp[262144 + idx] = c1st[e];
    }
  }
}

extern "C" void kernel_launch(void* const* d_in, const int* in_sizes, int n_in,
                              void* d_out, int out_size, void* d_ws, size_t ws_size,
                              hipStream_t stream) {
  (void)in_sizes; (void)n_in; (void)out_size;
  if (ws_size < (size_t)WS_NEEDED) return;

  const float* h0   = (const float*)d_in[1];
  const float* c0   = (const float*)d_in[2];
  const float* Wih0 = (const float*)d_in[3];
  const float* Whh0 = (const float*)d_in[4];
  const float* bih0 = (const float*)d_in[5];
  const float* bhh0 = (const float*)d_in[6];
  const float* Wih1 = (const float*)d_in[7];
  const float* Whh1 = (const float*)d_in[8];
  const float* bih1 = (const float*)d_in[9];
  const float* bhh1 = (const float*)d_in[10];
  const float* Wfc  = (const float*)d_in[11];
  const float* bfc  = (const float*)d_in[12];
  float* outp = (float*)d_out;
  char*  wsp  = (char*)d_ws;

  // zero barrier + slot counters (ws is re-poisoned to 0xAA before every
  // launch; end-of-dispatch flush of the memset makes zeros globally visible)
  hipMemsetAsync(d_ws, 0, WS_HBUF_OFF, stream);

  void* args[] = { &h0, &c0, &Wih0, &Whh0, &bih0, &bhh0, &Wih1, &Whh1,
                   &bih1, &bhh1, &Wfc, &bfc, &outp, &wsp };
  hipError_t e = hipLaunchCooperativeKernel((const void*)decoder_kernel,
                                            dim3(NBLK), dim3(NTHR),
                                            args, 0u, stream);
  if (e != hipSuccess) {
    // fallback: plain launch (256 blocks x 512 thr, 1/CU, co-resident)
    decoder_kernel<<<dim3(NBLK), dim3(NTHR), 0, stream>>>(
        h0, c0, Wih0, Whh0, bih0, bhh0, Wih1, Whh1, bih1, bhh1, Wfc, bfc, outp, wsp);
  }
}